// Round 1
// baseline (152.471 us; speedup 1.0000x reference)
//
#include <hip/hip_runtime.h>
#include <math.h>

#define EPSF 1e-8f

// Compose affine maps g(x)=A+Bx via inclusive suffix scan across the wave.
// After this, lane i holds f_i ∘ f_{i+1} ∘ ... ∘ f_63.
__device__ __forceinline__ void suffix_scan64(float& A, float& B, int lane) {
#pragma unroll
    for (int d = 1; d < 64; d <<= 1) {
        float Ao = __shfl_down(A, d);
        float Bo = __shfl_down(B, d);
        if (lane + d < 64) {
            A = fmaf(B, Ao, A);   // (self ∘ other): A + B*Ao
            B = B * Bo;
        }
    }
}

__global__ __launch_bounds__(256, 8)
void td_lambda_kernel(const float* __restrict__ raw_gamma,
                      const float* __restrict__ raw_lambd, int lam_off,
                      const float* __restrict__ values,
                      const float* __restrict__ rewards,
                      const int* __restrict__ dones,
                      float* __restrict__ out,
                      int B, int S, int rowBlocks)
{
    const float gamma = fmaxf(tanhf(raw_gamma[0]), EPSF);
    const int lane = threadIdx.x & 63;

    if ((int)blockIdx.x == rowBlocks) {
        // ---- srw (sum_reward_weights) block: wave 0 only ----
        if (threadIdx.x >= 64) return;
        const int NC = S / 64;

        // Pass 1: compute sum of w
        float carry = 1.0f;
        float partial = 0.0f;
        for (int c = NC - 1; c >= 0; --c) {
            int t = c * 64 + lane;
            float lam = fmaxf(tanhf(raw_lambd[lam_off + t]), EPSF);
            float A = gamma * (1.0f - lam);   // v_t = A + Bc*v_next
            float Bc = gamma * lam;
            suffix_scan64(A, Bc, lane);
            float v = fmaf(Bc, carry, A);
            partial += fmaxf(1.0f - v, EPSF);
            carry = __shfl(v, 0);
        }
#pragma unroll
        for (int d = 32; d; d >>= 1) partial += __shfl_xor(partial, d);
        float inv = 1.0f / fmaxf(partial / (float)S, EPSF);

        // Pass 2: recompute and store srw
        carry = 1.0f;
        size_t base = (size_t)B * (size_t)S;
        for (int c = NC - 1; c >= 0; --c) {
            int t = c * 64 + lane;
            float lam = fmaxf(tanhf(raw_lambd[lam_off + t]), EPSF);
            float A = gamma * (1.0f - lam);
            float Bc = gamma * lam;
            suffix_scan64(A, Bc, lane);
            float v = fmaf(Bc, carry, A);
            out[base + t] = fmaxf(1.0f - v, EPSF) * inv;
            carry = __shfl(v, 0);
        }
        return;
    }

    // ---- lambda_returns: one wave per batch row ----
    int b = blockIdx.x * 4 + (threadIdx.x >> 6);
    if (b >= B) return;

    const float* rrow = rewards + (size_t)b * S;
    const int*   drow = dones   + (size_t)b * S;
    const float* vrow = values  + (size_t)b * (S + 1);
    float*       orow = out     + (size_t)b * S;

    float carry = vrow[S];    // values[b, S] — init of reverse scan

    // 256 elements per chunk: 4 per lane, float4 loads (coalesced).
    for (int t0 = S - 256; t0 >= 0; t0 -= 256) {
        int tb = t0 + lane * 4;
        float4 r4 = *(const float4*)(rrow + tb);
        int4   d4 = *(const int4*)(drow + tb);
        // v_{t+1} — misaligned by 1 element, scalar loads (L1/L2 absorbs overlap)
        float v1 = vrow[tb + 1];
        float v2 = vrow[tb + 2];
        float v3 = vrow[tb + 3];
        float v4 = vrow[tb + 4];

        float a0, a1, a2, a3, b0, b1, b2, b3;
        {
            float lam, gd;
            gd  = gamma * (1.0f - (float)d4.x);
            lam = fmaxf(tanhf(raw_lambd[lam_off + tb + 0]), EPSF);
            b0 = gd * lam; a0 = fmaf(gd * (1.0f - lam), v1, r4.x);
            gd  = gamma * (1.0f - (float)d4.y);
            lam = fmaxf(tanhf(raw_lambd[lam_off + tb + 1]), EPSF);
            b1 = gd * lam; a1 = fmaf(gd * (1.0f - lam), v2, r4.y);
            gd  = gamma * (1.0f - (float)d4.z);
            lam = fmaxf(tanhf(raw_lambd[lam_off + tb + 2]), EPSF);
            b2 = gd * lam; a2 = fmaf(gd * (1.0f - lam), v3, r4.z);
            gd  = gamma * (1.0f - (float)d4.w);
            lam = fmaxf(tanhf(raw_lambd[lam_off + tb + 3]), EPSF);
            b3 = gd * lam; a3 = fmaf(gd * (1.0f - lam), v4, r4.w);
        }

        // Local composition over this lane's 4 maps: L = f0∘f1∘f2∘f3
        float A = a3, Bc = b3;
        A = fmaf(b2, A, a2); Bc *= b2;
        A = fmaf(b1, A, a1); Bc *= b1;
        A = fmaf(b0, A, a0); Bc *= b0;

        // Wave-wide suffix scan of the 64 local maps
        suffix_scan64(A, Bc, lane);

        // Exclusive suffix (maps strictly after this lane)
        float EA = __shfl_down(A, 1);
        float EB = __shfl_down(Bc, 1);
        if (lane == 63) { EA = 0.0f; EB = 1.0f; }

        float x  = fmaf(EB, carry, EA);   // ret_{tb+4}
        float o3 = fmaf(b3, x,  a3);
        float o2 = fmaf(b2, o3, a2);
        float o1 = fmaf(b1, o2, a1);
        float o0 = fmaf(b0, o1, a0);
        *(float4*)(orow + tb) = make_float4(o0, o1, o2, o3);

        carry = __shfl(o0, 0);            // ret_{t0} → carry for next chunk
    }
}

extern "C" void kernel_launch(void* const* d_in, const int* in_sizes, int n_in,
                              void* d_out, int out_size, void* d_ws, size_t ws_size,
                              hipStream_t stream) {
    const float* raw_gamma = (const float*)d_in[0];
    const float* raw_lambd = (const float*)d_in[1];
    const float* values    = (const float*)d_in[2];
    const float* rewards   = (const float*)d_in[3];
    const int*   dones     = (const int*)d_in[4];
    float* out = (float*)d_out;

    int n_v = in_sizes[2];           // B*(S+1)
    int n_r = in_sizes[3];           // B*S
    int B = n_v - n_r;               // 8192
    int S = n_r / B;                 // 1024
    int lam_off = in_sizes[1] - S;   // 0 here

    int rowBlocks = (B + 3) / 4;     // 4 waves/block, 1 row/wave
    dim3 grid(rowBlocks + 1);        // +1 block for srw
    dim3 block(256);
    td_lambda_kernel<<<grid, block, 0, stream>>>(
        raw_gamma, raw_lambd, lam_off, values, rewards, dones,
        out, B, S, rowBlocks);
}

// Round 2
// 152.161 us; speedup vs baseline: 1.0020x; 1.0020x over previous
//
#include <hip/hip_runtime.h>
#include <math.h>

#define EPSF 1e-8f

// values rows are only 4B-aligned (row stride S+1=1025 floats) — use an
// alignment-4 vector type so the compiler emits a HW-legal unaligned dwordx4.
typedef float fvec4 __attribute__((ext_vector_type(4), aligned(4)));

// Compose affine maps g(x)=A+Bx via inclusive suffix scan across the wave.
// After this, lane i holds f_i ∘ f_{i+1} ∘ ... ∘ f_63.
__device__ __forceinline__ void suffix_scan64(float& A, float& B, int lane) {
#pragma unroll
    for (int d = 1; d < 64; d <<= 1) {
        float Ao = __shfl_down(A, d);
        float Bo = __shfl_down(B, d);
        if (lane + d < 64) {
            A = fmaf(B, Ao, A);   // self ∘ other
            B = B * Bo;
        }
    }
}

// One small block: compute gl[t]=γλ_t, gol[t]=γ(1-λ_t) into ws, and emit the
// sum_reward_weights output (wave 0, single scan over S=1024).
__global__ __launch_bounds__(256)
void prep_kernel(const float* __restrict__ raw_gamma,
                 const float* __restrict__ raw_lambd, int lam_off,
                 float* __restrict__ gl, float* __restrict__ gol,
                 float* __restrict__ srw_out, int S)
{
    __shared__ float s_gl[1024];
    __shared__ float s_gol[1024];
    const float gamma = fmaxf(tanhf(raw_gamma[0]), EPSF);
    for (int t = threadIdx.x; t < S; t += 256) {
        float lam = fmaxf(tanhf(raw_lambd[lam_off + t]), EPSF);
        float g1 = gamma * lam;
        float g0 = gamma - g1;          // γ(1-λ)
        gl[t] = g1;  gol[t] = g0;
        s_gl[t] = g1; s_gol[t] = g0;
    }
    __syncthreads();
    if (threadIdx.x >= 64) return;
    const int lane = threadIdx.x;
    const int base = lane << 4;         // 16 per lane (S=1024)

    float a[16], b[16];
#pragma unroll
    for (int j = 0; j < 16; ++j) { a[j] = s_gol[base + j]; b[j] = s_gl[base + j]; }

    float A = a[15], Bc = b[15];
#pragma unroll
    for (int j = 14; j >= 0; --j) { A = fmaf(b[j], A, a[j]); Bc *= b[j]; }
    suffix_scan64(A, Bc, lane);
    float EA = __shfl_down(A, 1);
    float EB = __shfl_down(Bc, 1);
    if (lane == 63) { EA = 0.0f; EB = 1.0f; }

    float v = fmaf(EB, 1.0f, EA);       // v at t = base+16
    float w[16];
    float sum = 0.0f;
#pragma unroll
    for (int j = 15; j >= 0; --j) {
        v = fmaf(b[j], v, a[j]);
        w[j] = fmaxf(1.0f - v, EPSF);
        sum += w[j];
    }
#pragma unroll
    for (int d = 32; d; d >>= 1) sum += __shfl_xor(sum, d);
    float inv = 1.0f / fmaxf(sum / (float)S, EPSF);
#pragma unroll
    for (int j = 0; j < 16; ++j) srw_out[base + j] = w[j] * inv;
}

// One wave per batch row; 16 contiguous t per lane; single wave scan.
__global__ __launch_bounds__(256, 4)
void td_main(const float* __restrict__ gl, const float* __restrict__ gol,
             const float* __restrict__ values,
             const float* __restrict__ rewards,
             const int* __restrict__ dones,
             float* __restrict__ out, int B, int S)
{
    const int lane = threadIdx.x & 63;
    const int b = blockIdx.x * 4 + (threadIdx.x >> 6);
    if (b >= B) return;

    const float* rrow = rewards + (size_t)b * S;
    const int*   drow = dones   + (size_t)b * S;
    const float* vrow = values  + (size_t)b * (S + 1);
    float*       orow = out     + (size_t)b * S;
    const int base = lane << 4;

    // All loads issued up-front — no dependencies, maximal MLP.
    float4 r4[4]; int4 dd[4]; fvec4 v4[4]; float4 g1[4]; float4 g0[4];
#pragma unroll
    for (int k = 0; k < 4; ++k) {
        r4[k] = *(const float4*)(rrow + base + 4 * k);
        dd[k] = *(const int4*)(drow + base + 4 * k);
        v4[k] = *(const fvec4*)(vrow + base + 4 * k);   // v[base .. base+15]
        g1[k] = *(const float4*)(gl + base + 4 * k);
        g0[k] = *(const float4*)(gol + base + 4 * k);
    }
    float vS = vrow[S];
    float vb = __shfl_down(v4[0].x, 1);   // v[base+16] from next lane
    if (lane == 63) vb = vS;

    // Affine coefficients: ret_t = a_t + b_t * ret_{t+1}
    float a[16], bb[16];
#pragma unroll
    for (int k = 0; k < 4; ++k) {
        float vn0 = v4[k].y, vn1 = v4[k].z, vn2 = v4[k].w;
        float vn3 = (k < 3) ? v4[k + 1].x : vb;
        float vn[4] = {vn0, vn1, vn2, vn3};
        float rr[4] = {r4[k].x, r4[k].y, r4[k].z, r4[k].w};
        int   di[4] = {dd[k].x, dd[k].y, dd[k].z, dd[k].w};
        float G1[4] = {g1[k].x, g1[k].y, g1[k].z, g1[k].w};
        float G0[4] = {g0[k].x, g0[k].y, g0[k].z, g0[k].w};
#pragma unroll
        for (int j = 0; j < 4; ++j) {
            float nd = 1.0f - (float)di[j];
            bb[4 * k + j] = G1[j] * nd;
            a[4 * k + j]  = fmaf(G0[j] * vn[j], nd, rr[j]);
        }
    }

    // Lane-local composite of 16 maps (ordered t ascending → compose f_lo ∘ f_hi)
    float A = a[15], Bc = bb[15];
#pragma unroll
    for (int j = 14; j >= 0; --j) { A = fmaf(bb[j], A, a[j]); Bc *= bb[j]; }

    // One wave-wide suffix scan over the 64 lane composites
    suffix_scan64(A, Bc, lane);
    float EA = __shfl_down(A, 1);
    float EB = __shfl_down(Bc, 1);
    if (lane == 63) { EA = 0.0f; EB = 1.0f; }
    float x = fmaf(EB, vS, EA);          // ret at t = base+16

    float o[16];
#pragma unroll
    for (int j = 15; j >= 0; --j) {
        x = fmaf(bb[j], x, a[j]);
        o[j] = x;
    }
#pragma unroll
    for (int k = 0; k < 4; ++k)
        *(float4*)(orow + base + 4 * k) =
            make_float4(o[4 * k], o[4 * k + 1], o[4 * k + 2], o[4 * k + 3]);
}

extern "C" void kernel_launch(void* const* d_in, const int* in_sizes, int n_in,
                              void* d_out, int out_size, void* d_ws, size_t ws_size,
                              hipStream_t stream) {
    const float* raw_gamma = (const float*)d_in[0];
    const float* raw_lambd = (const float*)d_in[1];
    const float* values    = (const float*)d_in[2];
    const float* rewards   = (const float*)d_in[3];
    const int*   dones     = (const int*)d_in[4];
    float* out = (float*)d_out;

    int n_v = in_sizes[2];           // B*(S+1)
    int n_r = in_sizes[3];           // B*S
    int B = n_v - n_r;               // 8192
    int S = n_r / B;                 // 1024
    int lam_off = in_sizes[1] - S;

    float* gl  = (float*)d_ws;
    float* gol = gl + S;
    float* srw_out = out + (size_t)B * S;

    prep_kernel<<<1, 256, 0, stream>>>(raw_gamma, raw_lambd, lam_off,
                                       gl, gol, srw_out, S);
    td_main<<<(B + 3) / 4, 256, 0, stream>>>(gl, gol, values, rewards, dones,
                                             out, B, S);
}

// Round 4
// 146.837 us; speedup vs baseline: 1.0384x; 1.0363x over previous
//
#include <hip/hip_runtime.h>
#include <math.h>

#define EPSF 1e-8f

// values rows are only 4B-aligned (row stride S+1=1025 floats).
typedef float fvec4 __attribute__((ext_vector_type(4), aligned(4)));
// native clang vector (16B-aligned) — accepted by __builtin_nontemporal_store
typedef float nvec4 __attribute__((ext_vector_type(4)));

// Inclusive suffix scan of affine maps g(x)=A+Bx across the wave.
__device__ __forceinline__ void suffix_scan64(float& A, float& B, int lane) {
#pragma unroll
    for (int d = 1; d < 64; d <<= 1) {
        float Ao = __shfl_down(A, d);
        float Bo = __shfl_down(B, d);
        if (lane + d < 64) {
            A = fmaf(B, Ao, A);
            B = B * Bo;
        }
    }
}

// One wave per batch row. Row split into 4 coalesced chunks of 256:
// lane i owns t = 256c + 4i .. 4i+3 for c = 0..3. Four independent wave
// scans (interleaved), stitched by 3 scalar affine applications.
__global__ __launch_bounds__(256, 4)
void td_kernel(const float* __restrict__ raw_gamma,
               const float* __restrict__ raw_lambd, int lam_off,
               const float* __restrict__ values,
               const float* __restrict__ rewards,
               const int* __restrict__ dones,
               float* __restrict__ out,
               int B, int S, int rowBlocks)
{
    __shared__ float s_gl[1024];   // γ·λ_t
    __shared__ float s_gol[1024];  // γ·(1-λ_t)
    const float gamma = fmaxf(tanhf(raw_gamma[0]), EPSF);
    for (int t = threadIdx.x; t < S; t += 256) {
        float lam = fmaxf(tanhf(raw_lambd[lam_off + t]), EPSF);
        float g1 = gamma * lam;
        s_gl[t] = g1;
        s_gol[t] = gamma - g1;
    }
    __syncthreads();

    const int lane = threadIdx.x & 63;

    if ((int)blockIdx.x == rowBlocks) {
        // ---- sum_reward_weights: wave 0 of the extra block ----
        if (threadIdx.x >= 64) return;
        const int base = lane << 4;   // 16 per lane over S=1024
        float a[16], b[16];
#pragma unroll
        for (int j = 0; j < 16; ++j) { a[j] = s_gol[base + j]; b[j] = s_gl[base + j]; }
        float A = a[15], Bc = b[15];
#pragma unroll
        for (int j = 14; j >= 0; --j) { A = fmaf(b[j], A, a[j]); Bc *= b[j]; }
        suffix_scan64(A, Bc, lane);
        float EA = __shfl_down(A, 1);
        float EB = __shfl_down(Bc, 1);
        if (lane == 63) { EA = 0.0f; EB = 1.0f; }
        float v = EA + EB;            // applied to v_next=1.0
        float w[16], sum = 0.0f;
#pragma unroll
        for (int j = 15; j >= 0; --j) {
            v = fmaf(b[j], v, a[j]);
            w[j] = fmaxf(1.0f - v, EPSF);
            sum += w[j];
        }
#pragma unroll
        for (int d = 32; d; d >>= 1) sum += __shfl_xor(sum, d);
        float inv = 1.0f / fmaxf(sum / (float)S, EPSF);
        float* srw = out + (size_t)B * S;
#pragma unroll
        for (int j = 0; j < 16; ++j) srw[base + j] = w[j] * inv;
        return;
    }

    // ---- lambda_returns ----
    const int b = blockIdx.x * 4 + (threadIdx.x >> 6);
    if (b >= B) return;
    const int C = S >> 2;             // 256
    const int t0 = lane << 2;         // 4i

    const float* rrow = rewards + (size_t)b * S;
    const int*   drow = dones   + (size_t)b * S;
    const float* vrow = values  + (size_t)b * (S + 1);
    float*       orow = out     + (size_t)b * S;

    // All stream loads issued up-front, fully coalesced (1 KB / instr).
    float4 r4[4]; int4 d4[4]; fvec4 v4[4];
#pragma unroll
    for (int c = 0; c < 4; ++c) {
        int t = c * C + t0;
        r4[c] = *(const float4*)(rrow + t);
        d4[c] = *(const int4*)(drow + t);
        v4[c] = *(const fvec4*)(vrow + t + 1);   // v_{t+1}
    }
    float vS = vrow[S];

    // Affine coefficients: ret_t = a_t + b_t * ret_{t+1}
    float a[16], bb[16];
#pragma unroll
    for (int c = 0; c < 4; ++c) {
        const float4 G1 = *(const float4*)&s_gl[c * C + t0];
        const float4 G0 = *(const float4*)&s_gol[c * C + t0];
        float vn[4] = {v4[c].x, v4[c].y, v4[c].z, v4[c].w};
        float rr[4] = {r4[c].x, r4[c].y, r4[c].z, r4[c].w};
        int   di[4] = {d4[c].x, d4[c].y, d4[c].z, d4[c].w};
        float g1v[4] = {G1.x, G1.y, G1.z, G1.w};
        float g0v[4] = {G0.x, G0.y, G0.z, G0.w};
#pragma unroll
        for (int j = 0; j < 4; ++j) {
            float nd = 1.0f - (float)di[j];
            bb[c * 4 + j] = g1v[j] * nd;
            a[c * 4 + j]  = fmaf(g0v[j] * vn[j], nd, rr[j]);
        }
    }

    // Lane-local composite per chunk: L = f_t0 ∘ f_t0+1 ∘ f_t0+2 ∘ f_t0+3
    float A[4], Bc[4];
#pragma unroll
    for (int c = 0; c < 4; ++c) {
        A[c] = a[c * 4 + 3]; Bc[c] = bb[c * 4 + 3];
#pragma unroll
        for (int j = 2; j >= 0; --j) {
            A[c] = fmaf(bb[c * 4 + j], A[c], a[c * 4 + j]);
            Bc[c] *= bb[c * 4 + j];
        }
    }

    // Four interleaved wave-wide suffix scans (latency overlapped)
#pragma unroll
    for (int d = 1; d < 64; d <<= 1) {
        float Ao[4], Bo[4];
#pragma unroll
        for (int c = 0; c < 4; ++c) {
            Ao[c] = __shfl_down(A[c], d);
            Bo[c] = __shfl_down(Bc[c], d);
        }
        if (lane + d < 64) {
#pragma unroll
            for (int c = 0; c < 4; ++c) {
                A[c] = fmaf(Bc[c], Ao[c], A[c]);
                Bc[c] *= Bo[c];
            }
        }
    }

    // Exclusive suffixes + chunk composites (lane 0 of inclusive scan)
    float EA[4], EB[4], A0[4], B0[4];
#pragma unroll
    for (int c = 0; c < 4; ++c) {
        EA[c] = __shfl_down(A[c], 1);
        EB[c] = __shfl_down(Bc[c], 1);
        A0[c] = __shfl(A[c], 0);
        B0[c] = __shfl(Bc[c], 0);
    }
    if (lane == 63) {
#pragma unroll
        for (int c = 0; c < 4; ++c) { EA[c] = 0.0f; EB[c] = 1.0f; }
    }

    // Stitch chunk carries: ret at t=256(c+1)
    float x4 = vS;                       // ret_1024
    float x3 = fmaf(B0[3], x4, A0[3]);   // ret_768
    float x2 = fmaf(B0[2], x3, A0[2]);   // ret_512
    float x1 = fmaf(B0[1], x2, A0[1]);   // ret_256
    float xin[4] = {x1, x2, x3, x4};

    // Reconstruct and store (coalesced, non-temporal)
#pragma unroll
    for (int c = 0; c < 4; ++c) {
        float x  = fmaf(EB[c], xin[c], EA[c]);   // ret at 256c + 4i + 4
        float o3 = fmaf(bb[c * 4 + 3], x,  a[c * 4 + 3]);
        float o2 = fmaf(bb[c * 4 + 2], o3, a[c * 4 + 2]);
        float o1 = fmaf(bb[c * 4 + 1], o2, a[c * 4 + 1]);
        float o0 = fmaf(bb[c * 4 + 0], o1, a[c * 4 + 0]);
        nvec4 ov = {o0, o1, o2, o3};
        __builtin_nontemporal_store(ov, (nvec4*)(orow + c * C + t0));
    }
}

extern "C" void kernel_launch(void* const* d_in, const int* in_sizes, int n_in,
                              void* d_out, int out_size, void* d_ws, size_t ws_size,
                              hipStream_t stream) {
    const float* raw_gamma = (const float*)d_in[0];
    const float* raw_lambd = (const float*)d_in[1];
    const float* values    = (const float*)d_in[2];
    const float* rewards   = (const float*)d_in[3];
    const int*   dones     = (const int*)d_in[4];
    float* out = (float*)d_out;

    int n_v = in_sizes[2];           // B*(S+1)
    int n_r = in_sizes[3];           // B*S
    int B = n_v - n_r;               // 8192
    int S = n_r / B;                 // 1024
    int lam_off = in_sizes[1] - S;

    int rowBlocks = (B + 3) / 4;     // one wave per row, 4 waves/block
    td_kernel<<<rowBlocks + 1, 256, 0, stream>>>(
        raw_gamma, raw_lambd, lam_off, values, rewards, dones,
        out, B, S, rowBlocks);
}

// Round 5
// 144.767 us; speedup vs baseline: 1.0532x; 1.0143x over previous
//
#include <hip/hip_runtime.h>
#include <math.h>

#define EPSF 1e-8f

// values rows are only 4B-aligned (row stride S+1=1025 floats).
typedef float fvec4 __attribute__((ext_vector_type(4), aligned(4)));
// native clang vector — accepted by __builtin_nontemporal_store
typedef float nvec4 __attribute__((ext_vector_type(4)));

// Inclusive suffix scan of affine maps g(x)=A+Bx across the wave.
__device__ __forceinline__ void suffix_scan64(float& A, float& B, int lane) {
#pragma unroll
    for (int d = 1; d < 64; d <<= 1) {
        float Ao = __shfl_down(A, d);
        float Bo = __shfl_down(B, d);
        if (lane + d < 64) {
            A = fmaf(B, Ao, A);
            B = B * Bo;
        }
    }
}

// One wave per 4 batch rows, software-pipelined: prefetch row r+1 while
// scanning row r. Row split into 4 coalesced chunks of 256: lane i owns
// t = 256c + 4i .. 4i+3.
__global__ __launch_bounds__(256, 2)
void td_kernel(const float* __restrict__ raw_gamma,
               const float* __restrict__ raw_lambd, int lam_off,
               const float* __restrict__ values,
               const float* __restrict__ rewards,
               const int* __restrict__ dones,
               float* __restrict__ out,
               int B, int S, int rowBlocks)
{
    __shared__ float s_gl[1024];   // γ·λ_t
    const float gamma = fmaxf(tanhf(raw_gamma[0]), EPSF);
    for (int t = threadIdx.x; t < S; t += 256)
        s_gl[t] = gamma * fmaxf(tanhf(raw_lambd[lam_off + t]), EPSF);
    __syncthreads();

    const int lane = threadIdx.x & 63;

    if ((int)blockIdx.x == rowBlocks) {
        // ---- sum_reward_weights: wave 0 of the extra block ----
        if (threadIdx.x >= 64) return;
        const int base = lane << 4;   // 16 per lane over S=1024
        float a[16], b[16];
#pragma unroll
        for (int j = 0; j < 16; ++j) { b[j] = s_gl[base + j]; a[j] = gamma - b[j]; }
        float A = a[15], Bc = b[15];
#pragma unroll
        for (int j = 14; j >= 0; --j) { A = fmaf(b[j], A, a[j]); Bc *= b[j]; }
        suffix_scan64(A, Bc, lane);
        float EA = __shfl_down(A, 1);
        float EB = __shfl_down(Bc, 1);
        if (lane == 63) { EA = 0.0f; EB = 1.0f; }
        float v = EA + EB;            // applied to v_next=1.0
        float w[16], sum = 0.0f;
#pragma unroll
        for (int j = 15; j >= 0; --j) {
            v = fmaf(b[j], v, a[j]);
            w[j] = fmaxf(1.0f - v, EPSF);
            sum += w[j];
        }
#pragma unroll
        for (int d = 32; d; d >>= 1) sum += __shfl_xor(sum, d);
        float inv = 1.0f / fmaxf(sum / (float)S, EPSF);
        float* srw = out + (size_t)B * S;
#pragma unroll
        for (int j = 0; j < 16; ++j) srw[base + j] = w[j] * inv;
        return;
    }

    // ---- lambda_returns ----
    const int C = S >> 2;             // 256
    const int t0 = lane << 2;         // 4i
    const int b0 = (blockIdx.x * 4 + (threadIdx.x >> 6)) * 4;
    if (b0 >= B) return;

    // Row-invariant coefficients → registers (read LDS once per wave)
    float4 G1[4];
#pragma unroll
    for (int c = 0; c < 4; ++c) G1[c] = *(const float4*)&s_gl[c * C + t0];

    // Load row b0 (current buffers)
    float4 cr[4]; int4 cd[4]; fvec4 cv[4]; float cvS;
    {
        const float* rrow = rewards + (size_t)b0 * S;
        const int*   drow = dones   + (size_t)b0 * S;
        const float* vrow = values  + (size_t)b0 * (S + 1);
#pragma unroll
        for (int c = 0; c < 4; ++c) {
            int t = c * C + t0;
            cr[c] = *(const float4*)(rrow + t);
            cd[c] = *(const int4*)(drow + t);
            cv[c] = *(const fvec4*)(vrow + t + 1);
        }
        cvS = vrow[S];
    }

#pragma unroll 1
    for (int r = 0; r < 4; ++r) {
        const int b = b0 + r;
        // Prefetch next row while this row's scan runs
        float4 nr[4]; int4 nd[4]; fvec4 nv[4]; float nvS = 0.0f;
        if (r < 3 && b + 1 < B) {
            const float* rrow = rewards + (size_t)(b + 1) * S;
            const int*   drow = dones   + (size_t)(b + 1) * S;
            const float* vrow = values  + (size_t)(b + 1) * (S + 1);
#pragma unroll
            for (int c = 0; c < 4; ++c) {
                int t = c * C + t0;
                nr[c] = *(const float4*)(rrow + t);
                nd[c] = *(const int4*)(drow + t);
                nv[c] = *(const fvec4*)(vrow + t + 1);
            }
            nvS = vrow[S];
        }

        // Affine coefficients: ret_t = a_t + b_t * ret_{t+1}
        float a[16], bb[16];
#pragma unroll
        for (int c = 0; c < 4; ++c) {
            float vn[4] = {cv[c].x, cv[c].y, cv[c].z, cv[c].w};
            float rr[4] = {cr[c].x, cr[c].y, cr[c].z, cr[c].w};
            int   di[4] = {cd[c].x, cd[c].y, cd[c].z, cd[c].w};
            float g1v[4] = {G1[c].x, G1[c].y, G1[c].z, G1[c].w};
#pragma unroll
            for (int j = 0; j < 4; ++j) {
                float nd_ = 1.0f - (float)di[j];
                bb[c * 4 + j] = g1v[j] * nd_;
                a[c * 4 + j]  = fmaf((gamma - g1v[j]) * vn[j], nd_, rr[j]);
            }
        }

        // Lane-local composite per chunk
        float A[4], Bc[4];
#pragma unroll
        for (int c = 0; c < 4; ++c) {
            A[c] = a[c * 4 + 3]; Bc[c] = bb[c * 4 + 3];
#pragma unroll
            for (int j = 2; j >= 0; --j) {
                A[c] = fmaf(bb[c * 4 + j], A[c], a[c * 4 + j]);
                Bc[c] *= bb[c * 4 + j];
            }
        }

        // Four interleaved wave-wide suffix scans
#pragma unroll
        for (int d = 1; d < 64; d <<= 1) {
            float Ao[4], Bo[4];
#pragma unroll
            for (int c = 0; c < 4; ++c) {
                Ao[c] = __shfl_down(A[c], d);
                Bo[c] = __shfl_down(Bc[c], d);
            }
            if (lane + d < 64) {
#pragma unroll
                for (int c = 0; c < 4; ++c) {
                    A[c] = fmaf(Bc[c], Ao[c], A[c]);
                    Bc[c] *= Bo[c];
                }
            }
        }

        // Exclusive suffixes + chunk composites
        float EA[4], EB[4], A0[4], B0[4];
#pragma unroll
        for (int c = 0; c < 4; ++c) {
            EA[c] = __shfl_down(A[c], 1);
            EB[c] = __shfl_down(Bc[c], 1);
            A0[c] = __shfl(A[c], 0);
            B0[c] = __shfl(Bc[c], 0);
        }
        if (lane == 63) {
#pragma unroll
            for (int c = 0; c < 4; ++c) { EA[c] = 0.0f; EB[c] = 1.0f; }
        }

        // Stitch chunk carries
        float x4 = cvS;                      // ret_1024
        float x3 = fmaf(B0[3], x4, A0[3]);   // ret_768
        float x2 = fmaf(B0[2], x3, A0[2]);   // ret_512
        float x1 = fmaf(B0[1], x2, A0[1]);   // ret_256
        float xin[4] = {x1, x2, x3, x4};

        float* orow = out + (size_t)b * S;
#pragma unroll
        for (int c = 0; c < 4; ++c) {
            float x  = fmaf(EB[c], xin[c], EA[c]);
            float o3 = fmaf(bb[c * 4 + 3], x,  a[c * 4 + 3]);
            float o2 = fmaf(bb[c * 4 + 2], o3, a[c * 4 + 2]);
            float o1 = fmaf(bb[c * 4 + 1], o2, a[c * 4 + 1]);
            float o0 = fmaf(bb[c * 4 + 0], o1, a[c * 4 + 0]);
            nvec4 ov = {o0, o1, o2, o3};
            __builtin_nontemporal_store(ov, (nvec4*)(orow + c * C + t0));
        }

        // Rotate buffers
        if (r < 3) {
#pragma unroll
            for (int c = 0; c < 4; ++c) { cr[c] = nr[c]; cd[c] = nd[c]; cv[c] = nv[c]; }
            cvS = nvS;
        }
    }
}

extern "C" void kernel_launch(void* const* d_in, const int* in_sizes, int n_in,
                              void* d_out, int out_size, void* d_ws, size_t ws_size,
                              hipStream_t stream) {
    const float* raw_gamma = (const float*)d_in[0];
    const float* raw_lambd = (const float*)d_in[1];
    const float* values    = (const float*)d_in[2];
    const float* rewards   = (const float*)d_in[3];
    const int*   dones     = (const int*)d_in[4];
    float* out = (float*)d_out;

    int n_v = in_sizes[2];           // B*(S+1)
    int n_r = in_sizes[3];           // B*S
    int B = n_v - n_r;               // 8192
    int S = n_r / B;                 // 1024
    int lam_off = in_sizes[1] - S;

    // 4 rows per wave, 4 waves per block → 16 rows per block
    int rowBlocks = (B + 15) / 16;
    td_kernel<<<rowBlocks + 1, 256, 0, stream>>>(
        raw_gamma, raw_lambd, lam_off, values, rewards, dones,
        out, B, S, rowBlocks);
}

// Round 6
// 142.730 us; speedup vs baseline: 1.0682x; 1.0143x over previous
//
#include <hip/hip_runtime.h>
#include <math.h>

#define EPSF 1e-8f

// values rows are only 4B-aligned (row stride S+1=1025 floats).
typedef float fvec4 __attribute__((ext_vector_type(4), aligned(4)));
// native clang vector — accepted by __builtin_nontemporal_store
typedef float nvec4 __attribute__((ext_vector_type(4)));

// Inclusive suffix scan of affine maps g(x)=A+Bx across the wave.
__device__ __forceinline__ void suffix_scan64(float& A, float& B, int lane) {
#pragma unroll
    for (int d = 1; d < 64; d <<= 1) {
        float Ao = __shfl_down(A, d);
        float Bo = __shfl_down(B, d);
        if (lane + d < 64) {
            A = fmaf(B, Ao, A);
            B = B * Bo;
        }
    }
}

// Copy-granular decomposition: each wave owns ONE 256-element chunk of a row
// (3 KB in / 1 KB out per unit). The block's 4 waves cover one row; chunk
// composites are stitched via an 8-float LDS exchange + one barrier. Blocks
// grid-stride over rows with register double-buffering (prefetch row r+rb).
__global__ __launch_bounds__(256, 8)
void td_kernel(const float* __restrict__ raw_gamma,
               const float* __restrict__ raw_lambd, int lam_off,
               const float* __restrict__ values,
               const float* __restrict__ rewards,
               const int* __restrict__ dones,
               float* __restrict__ out,
               int B, int S, int rowBlocks)
{
    __shared__ float s_gl[1024];     // γ·λ_t
    __shared__ float sA[2][4], sB[2][4];   // per-iteration chunk composites
    const float gamma = fmaxf(tanhf(raw_gamma[0]), EPSF);
    for (int t = threadIdx.x; t < S; t += 256)
        s_gl[t] = gamma * fmaxf(tanhf(raw_lambd[lam_off + t]), EPSF);
    __syncthreads();

    const int lane = threadIdx.x & 63;
    const int c    = threadIdx.x >> 6;        // chunk index 0..3

    if ((int)blockIdx.x == rowBlocks) {
        // ---- sum_reward_weights: wave 0 of the extra block ----
        if (threadIdx.x >= 64) return;
        const int base = lane << 4;           // 16 per lane over S=1024
        float a[16], b[16];
#pragma unroll
        for (int j = 0; j < 16; ++j) { b[j] = s_gl[base + j]; a[j] = gamma - b[j]; }
        float A = a[15], Bc = b[15];
#pragma unroll
        for (int j = 14; j >= 0; --j) { A = fmaf(b[j], A, a[j]); Bc *= b[j]; }
        suffix_scan64(A, Bc, lane);
        float EA = __shfl_down(A, 1);
        float EB = __shfl_down(Bc, 1);
        if (lane == 63) { EA = 0.0f; EB = 1.0f; }
        float v = EA + EB;                    // applied to v_next = 1.0
        float w[16], sum = 0.0f;
#pragma unroll
        for (int j = 15; j >= 0; --j) {
            v = fmaf(b[j], v, a[j]);
            w[j] = fmaxf(1.0f - v, EPSF);
            sum += w[j];
        }
#pragma unroll
        for (int d = 32; d; d >>= 1) sum += __shfl_xor(sum, d);
        float inv = 1.0f / fmaxf(sum / (float)S, EPSF);
        float* srw = out + (size_t)B * S;
#pragma unroll
        for (int j = 0; j < 16; ++j) srw[base + j] = w[j] * inv;
        return;
    }

    // ---- lambda_returns ----
    const int t0 = (c << 8) + (lane << 2);    // this wave's element base
    const float4 G1 = *(const float4*)&s_gl[t0];
    const float g1v[4] = {G1.x, G1.y, G1.z, G1.w};
    const float g0v[4] = {gamma - G1.x, gamma - G1.y, gamma - G1.z, gamma - G1.w};

    // Load first row
    float4 cr; int4 cd; fvec4 cv; float cvS;
    {
        const int r = blockIdx.x;
        cr  = *(const float4*)(rewards + (size_t)r * S + t0);
        cd  = *(const int4*)(dones + (size_t)r * S + t0);
        cv  = *(const fvec4*)(values + (size_t)r * (S + 1) + t0 + 1);
        cvS = values[(size_t)r * (S + 1) + S];
    }

    int p = 0;
#pragma unroll 1
    for (int r = blockIdx.x; r < B; r += rowBlocks) {
        const int rn = r + rowBlocks;
        // Prefetch next row (overlaps this row's scan + barrier)
        float4 nr; int4 nd; fvec4 nv; float nvS = 0.0f;
        if (rn < B) {
            nr  = *(const float4*)(rewards + (size_t)rn * S + t0);
            nd  = *(const int4*)(dones + (size_t)rn * S + t0);
            nv  = *(const fvec4*)(values + (size_t)rn * (S + 1) + t0 + 1);
            nvS = values[(size_t)rn * (S + 1) + S];
        }

        // Affine coefficients: ret_t = a_t + b_t * ret_{t+1}
        float vn[4] = {cv.x, cv.y, cv.z, cv.w};
        float rr[4] = {cr.x, cr.y, cr.z, cr.w};
        int   di[4] = {cd.x, cd.y, cd.z, cd.w};
        float a[4], b[4];
#pragma unroll
        for (int j = 0; j < 4; ++j) {
            float ndn = 1.0f - (float)di[j];
            b[j] = g1v[j] * ndn;
            a[j] = fmaf(g0v[j] * vn[j], ndn, rr[j]);
        }

        // Lane-local composite of 4 maps, then one 64-lane suffix scan
        float A = a[3], Bc = b[3];
#pragma unroll
        for (int j = 2; j >= 0; --j) { A = fmaf(b[j], A, a[j]); Bc *= b[j]; }
        suffix_scan64(A, Bc, lane);
        float EA = __shfl_down(A, 1);
        float EB = __shfl_down(Bc, 1);
        if (lane == 63) { EA = 0.0f; EB = 1.0f; }
        if (lane == 0) { sA[p][c] = A; sB[p][c] = Bc; }
        __syncthreads();

        // Carry into this chunk: apply later chunks' composites to v_S
        float x = cvS;
#pragma unroll
        for (int j = 3; j >= 1; --j)
            if (j > c) x = fmaf(sB[p][j], x, sA[p][j]);   // wave-uniform branch

        float xi = fmaf(EB, x, EA);           // ret at t0+4
        float o3 = fmaf(b[3], xi, a[3]);
        float o2 = fmaf(b[2], o3, a[2]);
        float o1 = fmaf(b[1], o2, a[1]);
        float o0 = fmaf(b[0], o1, a[0]);
        nvec4 ov = {o0, o1, o2, o3};
        __builtin_nontemporal_store(ov, (nvec4*)(out + (size_t)r * S + t0));

        if (rn < B) { cr = nr; cd = nd; cv = nv; cvS = nvS; }
        p ^= 1;
    }
}

extern "C" void kernel_launch(void* const* d_in, const int* in_sizes, int n_in,
                              void* d_out, int out_size, void* d_ws, size_t ws_size,
                              hipStream_t stream) {
    const float* raw_gamma = (const float*)d_in[0];
    const float* raw_lambd = (const float*)d_in[1];
    const float* values    = (const float*)d_in[2];
    const float* rewards   = (const float*)d_in[3];
    const int*   dones     = (const int*)d_in[4];
    float* out = (float*)d_out;

    int n_v = in_sizes[2];           // B*(S+1)
    int n_r = in_sizes[3];           // B*S
    int B = n_v - n_r;               // 8192
    int S = n_r / B;                 // 1024
    int lam_off = in_sizes[1] - S;

    // One block per row-slot; blocks grid-stride over B rows (4 iters each).
    int rowBlocks = 2048;
    if (rowBlocks > B) rowBlocks = B;
    td_kernel<<<rowBlocks + 1, 256, 0, stream>>>(
        raw_gamma, raw_lambd, lam_off, values, rewards, dones,
        out, B, S, rowBlocks);
}